// Round 2
// baseline (133.235 us; speedup 1.0000x reference)
//
#include <hip/hip_runtime.h>

// MLPAttention B=4, LQ=128, LK=1024, D=512, U=256, fp32.
// scores(i,j) = sum_u v_u * tanh(q_iu + k_uj);  tanh(x) = 1 - 2/(1+e^{2x})
// => scores = SV - 2*sum_u v_u/(1 + Eq_iu*Ek_uj),  Eq=e^{2q}, Ek=e^{2k}, SV=sum v
// K1 proj_mfma: fp16 MFMA NT-GEMM, epilogue exp(2x) -> Eq, EkT (transposed).
// R12 split at the softmax boundary (V-reuse tiling):
//  K2a scores_exp: phase A (rcp-based scores) + den reduce; writes NORMALIZED
//     P[b][i][j] (2 MB) to ws. 256 blocks x 1024 thr, 2 rows/block. VALU/trans
//     bound (~137M v_rcp_f32) — this is the irreducible score cost.
//  K2b pv_gemm: P @ V with real output tiling: block = (b, 16 rows, 64 cols),
//     P row-panel (64KB, +4 pad: conflict-free) in LDS, V float4 loads shared
//     by 4 row-groups/wave. V bytes/CU: 2 MB -> 256 KB (8x reuse; the R10/R11
//     neutral results showed per-CU V load volume, not cache level, is what
//     matters). FLOP floor 3.4 us.
// History: R8 fused 114.8us; R9/R10 structural variants neutral-to-worse
// (did not change V volume); R11 XCD swizzle neutral (confirmed not
// L2-capacity-bound). Fill of 268MB ws re-poison (~43us) is harness-fixed.

typedef _Float16 half8 __attribute__((ext_vector_type(8)));
typedef float floatx4 __attribute__((ext_vector_type(4)));

#define EQ_OFF   0
#define EKT_OFF  (512 * 256)
#define P_OFF    (512 * 256 + 4 * 256 * 1024)

__global__ __launch_bounds__(256) void proj_mfma(
    const float* __restrict__ query, const float* __restrict__ key,
    const float* __restrict__ W_q, const float* __restrict__ W_k,
    const int* __restrict__ vlen, float* __restrict__ Eq,
    float* __restrict__ EkT) {
  // 64(M) x 64(N) tile, K=512 in 16 steps of BK=32. 256 thr = 4 waves (2x2).
  __shared__ __align__(16) _Float16 As[64 * 32];
  __shared__ __align__(16) _Float16 Bs[64 * 32];
  const int tid = threadIdx.x;
  const int mb = blockIdx.x;   // 0..7 q-part (m-tiles), 8..71 k-part (j-tiles)
  const int u0 = blockIdx.y * 64;
  const bool qpart = mb < 8;
  const float *Ag, *Bg;
  int kbatch = 0, j0 = 0, m0 = 0;
  if (qpart) {
    m0 = mb * 64;
    Ag = query + (size_t)m0 * 512;   // A rows = query rows (M = m)
    Bg = W_q + (size_t)u0 * 512;     // B rows = W_q rows   (N = u)
  } else {
    const int g0 = (mb - 8) * 64;
    kbatch = g0 >> 10;
    j0 = g0 & 1023;
    if (j0 >= vlen[kbatch]) return;  // fully-masked key tile
    Ag = W_k + (size_t)u0 * 512;     // A rows = W_k rows (M = u)
    Bg = key + (size_t)g0 * 512;     // B rows = key rows (N = j)
  }

  const int lrow = tid >> 2, lkq = (tid & 3) * 8;
  const float* Ags = Ag + lrow * 512 + lkq;
  const float* Bgs = Bg + lrow * 512 + lkq;
  _Float16* Ads = As + lrow * 32 + lkq;
  _Float16* Bds = Bs + lrow * 32 + lkq;

  const int lane = tid & 63;
  const int wid = tid >> 6;
  const int wm = (wid & 1) * 32, wn = (wid >> 1) * 32;
  const int frow = lane & 15;
  const int fk = (lane >> 4) * 8;

  floatx4 acc[2][2] = {{{0.f, 0.f, 0.f, 0.f}, {0.f, 0.f, 0.f, 0.f}},
                       {{0.f, 0.f, 0.f, 0.f}, {0.f, 0.f, 0.f, 0.f}}};

  float4 ra0 = *(const float4*)Ags;
  float4 ra1 = *(const float4*)(Ags + 4);
  float4 rb0 = *(const float4*)Bgs;
  float4 rb1 = *(const float4*)(Bgs + 4);

  for (int kb = 0; kb < 16; ++kb) {
    half8 ha, hb;
    ha[0] = (_Float16)ra0.x; ha[1] = (_Float16)ra0.y;
    ha[2] = (_Float16)ra0.z; ha[3] = (_Float16)ra0.w;
    ha[4] = (_Float16)ra1.x; ha[5] = (_Float16)ra1.y;
    ha[6] = (_Float16)ra1.z; ha[7] = (_Float16)ra1.w;
    hb[0] = (_Float16)rb0.x; hb[1] = (_Float16)rb0.y;
    hb[2] = (_Float16)rb0.z; hb[3] = (_Float16)rb0.w;
    hb[4] = (_Float16)rb1.x; hb[5] = (_Float16)rb1.y;
    hb[6] = (_Float16)rb1.z; hb[7] = (_Float16)rb1.w;
    __syncthreads();  // prior iter's fragment reads complete
    *(half8*)Ads = ha;
    *(half8*)Bds = hb;
    __syncthreads();
    if (kb + 1 < 16) {
      ra0 = *(const float4*)(Ags + (kb + 1) * 32);
      ra1 = *(const float4*)(Ags + (kb + 1) * 32 + 4);
      rb0 = *(const float4*)(Bgs + (kb + 1) * 32);
      rb1 = *(const float4*)(Bgs + (kb + 1) * 32 + 4);
    }
    half8 a0 = *(const half8*)(As + (wm + frow) * 32 + fk);
    half8 a1 = *(const half8*)(As + (wm + 16 + frow) * 32 + fk);
    half8 b0 = *(const half8*)(Bs + (wn + frow) * 32 + fk);
    half8 b1 = *(const half8*)(Bs + (wn + 16 + frow) * 32 + fk);
    acc[0][0] = __builtin_amdgcn_mfma_f32_16x16x32_f16(a0, b0, acc[0][0], 0, 0, 0);
    acc[0][1] = __builtin_amdgcn_mfma_f32_16x16x32_f16(a0, b1, acc[0][1], 0, 0, 0);
    acc[1][0] = __builtin_amdgcn_mfma_f32_16x16x32_f16(a1, b0, acc[1][0], 0, 0, 0);
    acc[1][1] = __builtin_amdgcn_mfma_f32_16x16x32_f16(a1, b1, acc[1][1], 0, 0, 0);
  }

  // C/D layout: col = lane&15, row = (lane>>4)*4 + reg
  const int rbase = (lane >> 4) * 4;
  const int col = lane & 15;
#pragma unroll
  for (int mi = 0; mi < 2; ++mi)
#pragma unroll
    for (int ni = 0; ni < 2; ++ni)
#pragma unroll
      for (int r = 0; r < 4; ++r) {
        const int R = wm + mi * 16 + rbase + r;   // M index
        const int C = wn + ni * 16 + col;         // N index
        const float e = __expf(2.f * acc[mi][ni][r]);
        if (qpart)
          Eq[(m0 + R) * 256 + u0 + C] = e;
        else
          EkT[kbatch * 262144 + (u0 + R) * 1024 + j0 + C] = e;
      }
}

__global__ __launch_bounds__(1024) void scores_exp(
    const float* __restrict__ Eq, const float* __restrict__ EkT,
    const float* __restrict__ vvec, const int* __restrict__ valid_len,
    float* __restrict__ P) {
  // block = (b, 2 query rows); 1024 thr (16 waves). Writes normalized P.
  __shared__ float4 QV[256];          // (Eq_row0, Eq_row1, -2*v, 0)
  __shared__ float2 red[16];
  const int tid = threadIdx.x;
  const int b = blockIdx.x >> 6;
  const int i0 = (blockIdx.x & 63) * 2;
  const int vl = valid_len[b];

  // stage QV; reduce SV = sum_u v_u once (hoisted out of the u-loop)
  float vv = 0.f;
  if (tid < 256) {
    vv = vvec[tid];
    QV[tid] = make_float4(Eq[(b * 128 + i0) * 256 + tid],
                          Eq[(b * 128 + i0 + 1) * 256 + tid], -2.f * vv, 0.f);
  }
  float sv = vv;
#pragma unroll
  for (int off = 32; off > 0; off >>= 1) sv += __shfl_xor(sv, off, 64);
  if ((tid & 63) == 0) red[tid >> 6] = make_float2(sv, 0.f);
  __syncthreads();  // publishes QV and red
  float SV = 0.f;
#pragma unroll
  for (int w = 0; w < 16; ++w) SV += red[w].x;

  // ---- Phase A: p = exp(score) for j = tid (no max-pass; |s| <= ~26) ----
  const int j = tid;
  float p0 = 0.f, p1 = 0.f;
  if (j < vl) {
    float a0 = 0.f, a1 = 0.f;
    const float* kp = EkT + b * 262144 + j;
#pragma unroll 8
    for (int u = 0; u < 256; ++u) {
      float ek = kp[u << 10];  // coalesced 256B/wave per u
      float4 q = QV[u];        // LDS b128 broadcast (cheap)
      float r0 = __builtin_amdgcn_rcpf(fmaf(q.x, ek, 1.f));
      float r1 = __builtin_amdgcn_rcpf(fmaf(q.y, ek, 1.f));
      a0 = fmaf(q.z, r0, a0);
      a1 = fmaf(q.z, r1, a1);
    }
    p0 = __expf(SV + a0);
    p1 = __expf(SV + a1);
  }

  // fused den reduce for both rows
  float2 pp = make_float2(p0, p1);
#pragma unroll
  for (int off = 32; off > 0; off >>= 1) {
    pp.x += __shfl_xor(pp.x, off, 64);
    pp.y += __shfl_xor(pp.y, off, 64);
  }
  __syncthreads();  // red[] reuse: all SV reads complete
  if ((tid & 63) == 0) red[tid >> 6] = pp;
  __syncthreads();  // publishes red
  float den0 = 0.f, den1 = 0.f;
#pragma unroll
  for (int w = 0; w < 16; ++w) { den0 += red[w].x; den1 += red[w].y; }

  // normalized P write (zeros beyond vl — K2b loops over padded region)
  const float rd0 = __builtin_amdgcn_rcpf(den0);
  const float rd1 = __builtin_amdgcn_rcpf(den1);
  float* Pr = P + (size_t)(b * 128 + i0) * 1024 + j;
  Pr[0] = p0 * rd0;
  Pr[1024] = p1 * rd1;
}

__global__ __launch_bounds__(256) void pv_gemm(
    const float* __restrict__ P, const float* __restrict__ value,
    const int* __restrict__ valid_len, float* __restrict__ out) {
  // block = (b, 16-row tile, 64-col tile): 4 x 8 x 8 = 256 blocks.
  // ct in low bits of blockIdx -> each XCD-class hosts one V col-slice.
  __shared__ float Ps[16 * 1028];  // 16 P rows, +4 pad (conflict-free reads)
  const int tid = threadIdx.x;
  const int ct = blockIdx.x & 7;
  const int rt = (blockIdx.x >> 3) & 7;
  const int b  = blockIdx.x >> 6;
  const int i0 = rt * 16;
  const int vl = valid_len[b];

  // stage P[16][1024] panel (64 KB), coalesced 4KB rows
  const float* Pg = P + (size_t)(b * 128 + i0) * 1024 + tid * 4;
#pragma unroll
  for (int rr = 0; rr < 16; ++rr) {
    float4 x = *(const float4*)(Pg + rr * 1024);
    *(float4*)(Ps + rr * 1028 + tid * 4) = x;
  }
  __syncthreads();

  const int r = tid >> 4;          // 0..15 row within tile
  const int cq = tid & 15;         // 0..15 -> col = ct*64 + cq*4
  const float* Vp = value + (size_t)b * 524288 + ct * 64 + cq * 4;
  const float* Pr = Ps + r * 1028;
  float4 acc = make_float4(0.f, 0.f, 0.f, 0.f);
  const int vlr = min(1024, (vl + 3) & ~3);  // P==0 beyond vl
#pragma unroll 2
  for (int j = 0; j < vlr; j += 4) {
    float4 pv = *(const float4*)(Pr + j);            // 4 addrs/wave, banks 4 apart
    float4 v0 = *(const float4*)(Vp + (size_t)(j + 0) * 512);  // 256B/wave, 4x bcast
    float4 v1 = *(const float4*)(Vp + (size_t)(j + 1) * 512);
    float4 v2 = *(const float4*)(Vp + (size_t)(j + 2) * 512);
    float4 v3 = *(const float4*)(Vp + (size_t)(j + 3) * 512);
    acc.x = fmaf(pv.x, v0.x, acc.x); acc.y = fmaf(pv.x, v0.y, acc.y);
    acc.z = fmaf(pv.x, v0.z, acc.z); acc.w = fmaf(pv.x, v0.w, acc.w);
    acc.x = fmaf(pv.y, v1.x, acc.x); acc.y = fmaf(pv.y, v1.y, acc.y);
    acc.z = fmaf(pv.y, v1.z, acc.z); acc.w = fmaf(pv.y, v1.w, acc.w);
    acc.x = fmaf(pv.z, v2.x, acc.x); acc.y = fmaf(pv.z, v2.y, acc.y);
    acc.z = fmaf(pv.z, v2.z, acc.z); acc.w = fmaf(pv.z, v2.w, acc.w);
    acc.x = fmaf(pv.w, v3.x, acc.x); acc.y = fmaf(pv.w, v3.y, acc.y);
    acc.z = fmaf(pv.w, v3.z, acc.z); acc.w = fmaf(pv.w, v3.w, acc.w);
  }
  *(float4*)(out + (size_t)(b * 128 + i0 + r) * 512 + ct * 64 + cq * 4) = acc;
}

extern "C" void kernel_launch(void* const* d_in, const int* in_sizes, int n_in,
                              void* d_out, int out_size, void* d_ws, size_t ws_size,
                              hipStream_t stream) {
  const float* query = (const float*)d_in[0];
  const float* key   = (const float*)d_in[1];
  const float* value = (const float*)d_in[2];
  const int*   vlen  = (const int*)d_in[3];
  const float* W_q   = (const float*)d_in[4];
  const float* W_k   = (const float*)d_in[5];
  const float* v     = (const float*)d_in[6];
  float* out = (float*)d_out;

  float* ws  = (float*)d_ws;
  float* Eq  = ws + EQ_OFF;    // 512x256
  float* EkT = ws + EKT_OFF;   // 4x256x1024
  float* P   = ws + P_OFF;     // 4x128x1024 normalized attn weights

  proj_mfma<<<dim3(72, 4), 256, 0, stream>>>(query, key, W_q, W_k, vlen, Eq, EkT);
  scores_exp<<<256, 1024, 0, stream>>>(Eq, EkT, v, vlen, P);
  pv_gemm<<<256, 256, 0, stream>>>(P, value, vlen, out);
}